// Round 16
// baseline (937.548 us; speedup 1.0000x reference)
//
#include <hip/hip_runtime.h>
#include <math.h>

#define EPS 1e-5f

typedef unsigned short u16;
typedef unsigned int u32;
typedef __attribute__((ext_vector_type(8))) short short8b;   // 8 x bf16 bits
typedef __attribute__((ext_vector_type(4))) float f32x4;

static inline int cdiv(long long a, int b) { return (int)((a + b - 1) / b); }

__device__ __forceinline__ float sgnf(float w) {
    return (w > 0.f) ? 1.f : ((w < 0.f) ? -1.f : 0.f);
}

// round-to-nearest-even fp32 -> bf16 bits
__device__ __forceinline__ u16 bf16_rne(float v) {
    u32 u = __float_as_uint(v);
    return (u16)((u + 0x7FFFu + ((u >> 16) & 1u)) >> 16);
}
__device__ __forceinline__ void split_bf16(float v, u16& h, u16& l) {
    h = bf16_rne(v);
    float hf = __uint_as_float((u32)h << 16);
    l = bf16_rne(v - hf);
}

// ---------------- prep kernels ----------------

// fp32 path prep (L1): wst[co/16][ci][k][co%16] = sign(w[co][ci][k])
__global__ void prep_conv_w(const float* __restrict__ w, float* __restrict__ wst,
                            int CO, int CI)
{
    int idx = blockIdx.x * blockDim.x + threadIdx.x;
    int n = CO * CI * 9;
    if (idx >= n) return;
    int k  = idx % 9;
    int ci = (idx / 9) % CI;
    int co = idx / (9 * CI);
    wst[((((co >> 4) * CI + ci) * 9 + k) << 4) + (co & 15)] = sgnf(w[idx]);
}

// conv MFMA B-fragment prep: per (ncg,tap,cis) slab of 512 u16:
// [lane][j] = sign(w[co=ncg*16+(lane&15)][ci=cis*32+((lane>>4)&3)*8+j][tap]) as bf16
__global__ void prep_wfrag(const float* __restrict__ w, u16* __restrict__ wB,
                           int CO, int CI)
{
    int idx = blockIdx.x * blockDim.x + threadIdx.x;
    int n = CO * CI * 9;
    if (idx >= n) return;
    int tap = idx % 9;
    int ci  = (idx / 9) % CI;
    int co  = idx / (9 * CI);
    int CIS = CI >> 5;
    int ncg = co >> 4;
    int l   = (co & 15) | (((ci >> 3) & 3) << 4);
    int j   = ci & 7;
    int cis = ci >> 5;
    size_t off = (((size_t)(ncg * 9 + tap) * CIS + cis) * 64 + l) * 8 + j;
    float wv = w[idx];
    wB[off] = wv > 0.f ? (u16)0x3F80 : (wv < 0.f ? (u16)0xBF80 : (u16)0);
}

// GEMM B-fragment prep for FC layers. logical W[o][k], o padded to OUTP.
// mode 0: src = w[o*K + k]. mode 1 (L6, NHWC features): k = tap*512 + ci,
// src = w[(o*512 + ci)*9 + tap].
__global__ void prep_gemm_wfrag(const float* __restrict__ w, u16* __restrict__ frag,
                                int OUT, int K, int OUTP, int mode)
{
    long long idx = (long long)blockIdx.x * blockDim.x + threadIdx.x;
    long long n = (long long)OUTP * K;
    if (idx >= n) return;
    int k = (int)(idx % K);
    int o = (int)(idx / K);
    u16 b = 0;
    if (o < OUT) {
        float wv;
        if (mode == 1) {
            int ci = k & 511, tap = k >> 9;
            wv = w[((size_t)o * 512 + ci) * 9 + tap];
        } else {
            wv = w[(size_t)o * K + k];
        }
        b = wv > 0.f ? (u16)0x3F80 : (wv < 0.f ? (u16)0xBF80 : (u16)0);
    }
    int KS = K >> 5;
    int ncg = o >> 4;
    int lane = (o & 15) | (((k >> 3) & 3) << 4);
    int j = k & 7, ks = k >> 5;
    frag[((size_t)(ncg * KS + ks) * 64 + lane) * 8 + j] = b;
}

__global__ void bn_prep(const float* __restrict__ bias, const float* __restrict__ g,
                        const float* __restrict__ be, const float* __restrict__ m,
                        const float* __restrict__ v,
                        float* __restrict__ sc, float* __restrict__ sh, int CO)
{
    int i = blockIdx.x * blockDim.x + threadIdx.x;
    if (i >= CO) return;
    float s = g[i] * rsqrtf(v[i] + EPS);
    sc[i] = s;
    sh[i] = be[i] - m[i] * s + bias[i] * s;
}

// ---------------- halo-staged MFMA conv + bn + relu (+ fused 2x2 pool) ------
// Double-buffered LDS, write-before-compute, ONE barrier per ci-slab:
//   stage(cs+1 -> buf^1); compute(cs, buf); barrier
// Staged data never lives in registers across compute (no spill — R8/R12
// lesson); no global_load_lds drain (R11/R13 lesson); waves desynchronize
// inside the barrier-free region so one wave's staging loads overlap
// another's MFMAs.
// OUTMODE: 0 = f32 NHWC, 1 = hi/lo NHWC, 2 = fused 2x2 maxpool -> hi/lo NHWC.
// POOL trick: m-index is pool-window-major; C/D layout gives each lane 4
// consecutive m rows -> whole 2x2 window in-register (3 fmax).
template<int CI, int CO, int IH, int TMR, int MSPW, int OUTMODE>
__global__ __launch_bounds__(256) void conv_mfma_halo(
    const u16* __restrict__ xhi, const u16* __restrict__ xlo,
    const u16* __restrict__ wB,
    const float* __restrict__ scale, const float* __restrict__ shift,
    float* __restrict__ yf, u16* __restrict__ yhi, u16* __restrict__ ylo)
{
    constexpr int IW = IH, OH = IH - 2, OW = OH, PLANE = OH * OW, IPLANE = IH * IW;
    constexpr int TM = TMR * OW;            // output px per tile
    constexpr int TILES = PLANE / TM;
    static_assert(PLANE % TM == 0, "tile");
    constexpr int PX = (TMR + 2) * IW;      // staged px per slab
    constexpr int CIS = CI / 32;
    constexpr int NSUB = (TM + 15) / 16;
    static_assert(NSUB <= 4 * MSPW, "slots");
    static_assert(OUTMODE != 2 || (TMR % 2 == 0 && OW % 2 == 0), "pool");
    constexpr int NBN = CO / 128;           // n-blocks (8 co-tiles each)
    constexpr int PLB = PX * 64;            // bytes per hi/lo plane per buffer
    constexpr int BUFB = 2 * PLB;           // hi+lo per buffer
    constexpr int PWT = OW / 2;             // pooled width
    constexpr int NQ  = (TMR / 2) * PWT;    // pool windows per tile
    constexpr int PPLANE = (OH / 2) * (OW / 2);

    __shared__ __align__(16) u16 As[2 * 2 * PX * 32];   // [buf][plane][PX][32]

    const int gid  = blockIdx.x;
    const int nb   = gid % NBN;
    const int tw   = gid / NBN;
    const int simg = tw / TILES;
    const int tile = tw - simg * TILES;
    const int ncg0 = nb * 8;
    const int t = threadIdx.x, lane = t & 63, wv = t >> 6;
    const long long gpix0 = (long long)simg * IPLANE + (long long)tile * TMR * IW;

    // per-slot LDS pixel base (window-local), clamped; m->px mapping
    int lpb[MSPW];
    #pragma unroll
    for (int s = 0; s < MSPW; ++s) {
        int st = wv * MSPW + s;
        int m = st * 16 + (lane & 15);
        if constexpr (OUTMODE == 2) {
            int q = m >> 2, r = m & 3;
            if (q > NQ - 1) q = NQ - 1;
            int pr = q / PWT, pc = q - pr * PWT;
            lpb[s] = (2 * pr + (r >> 1)) * IW + 2 * pc + (r & 1);
        } else {
            int p = (m > TM - 1) ? (TM - 1) : m;
            int pr = p / OW, pc = p - pr * OW;
            lpb[s] = pr * IW + pc;
        }
    }

    f32x4 acc[MSPW][8];
    #pragma unroll
    for (int s = 0; s < MSPW; ++s)
        #pragma unroll
        for (int n = 0; n < 8; ++n)
            #pragma unroll
            for (int r = 0; r < 4; ++r)
                acc[s][n][r] = 0.f;

    // stage one ci-slab into buffer buf: load + ds_write immediately
    // (no register residency across compute), swizzled, coalesced.
    auto stage = [&](int cs, int buf) {
        char* base = (char*)As + buf * BUFB;
        for (int u = t; u < PX * 8; u += 256) {
            int lp = u >> 3, sub = u & 7, pl = sub >> 2, cib = sub & 3;
            const u16* sp = pl ? xlo : xhi;
            uint4 v = *(const uint4*)(sp + (gpix0 + lp) * CI + (cs << 5) + (cib << 3));
            *(uint4*)(base + pl * PLB + lp * 64 + ((cib ^ ((lp >> 1) & 3)) << 4)) = v;
        }
    };

    stage(0, 0);
    __syncthreads();

    for (int cs = 0; cs < CIS; ++cs) {
        const int cur = cs & 1;
        const bool more = (cs + 1 < CIS);
        if (more) stage(cs + 1, cur ^ 1);   // writes other buffer; overlaps
                                            // other waves' compute below
        const char* Ab = (char*)As + cur * BUFB;
        // ---- sweep 9 taps from LDS ----
        #pragma unroll
        for (int tap = 0; tap < 9; ++tap) {
            const int kh = tap / 3, kw = tap - 3 * (tap / 3);
            short8b bfr[8];
            #pragma unroll
            for (int n = 0; n < 8; ++n)
                bfr[n] = *(const short8b*)(wB +
                    (((size_t)((ncg0 + n) * 9 + tap) * CIS + cs) << 9) + (lane << 3));
            #pragma unroll
            for (int s = 0; s < MSPW; ++s) {
                const int lp  = lpb[s] + kh * IW + kw;
                const int off = lp * 64 + (((lane >> 4) ^ ((lp >> 1) & 3)) << 4);
                short8b ah = *(const short8b*)(Ab + off);
                short8b al = *(const short8b*)(Ab + PLB + off);
                #pragma unroll
                for (int n = 0; n < 8; ++n) {
                    acc[s][n] = __builtin_amdgcn_mfma_f32_16x16x32_bf16(ah, bfr[n], acc[s][n], 0, 0, 0);
                    acc[s][n] = __builtin_amdgcn_mfma_f32_16x16x32_bf16(al, bfr[n], acc[s][n], 0, 0, 0);
                }
            }
        }
        if (more) __syncthreads();          // buf^1 fully written -> next iter
    }

    // ---- epilogue (C/D mapping: col=lane&15 -> co, row=(lane>>4)*4+r -> m) ----
    const int mrow = (lane >> 4) << 2;
    #pragma unroll
    for (int s = 0; s < MSPW; ++s) {
        const int st = wv * MSPW + s;
        if constexpr (OUTMODE == 2) {
            // lane holds m = st*16 + mrow + (0..3) = window q = st*4 + (lane>>4)
            int q = st * 4 + (lane >> 4);
            if (q > NQ - 1) q = NQ - 1;
            const int pr = q / PWT, pc = q - pr * PWT;
            const int gq = (tile * (TMR / 2) + pr) * PWT + pc;
            #pragma unroll
            for (int n = 0; n < 8; ++n) {
                const int co = ((ncg0 + n) << 4) + (lane & 15);
                const float sc_ = scale[co], sh_ = shift[co];
                float vmax = 0.f;   // relu'd values are >= 0
                #pragma unroll
                for (int r = 0; r < 4; ++r) {
                    float val = fmaxf(fmaf(acc[s][n][r], sc_, sh_), 0.f);
                    vmax = fmaxf(vmax, val);
                }
                const size_t o = ((size_t)simg * PPLANE + gq) * CO + co;
                u16 h, l; split_bf16(vmax, h, l);
                yhi[o] = h; ylo[o] = l;   // duplicate lanes write identical bytes
            }
        } else {
            #pragma unroll
            for (int n = 0; n < 8; ++n) {
                const int co = ((ncg0 + n) << 4) + (lane & 15);
                const float sc_ = scale[co], sh_ = shift[co];
                #pragma unroll
                for (int r = 0; r < 4; ++r) {
                    const int pl_ = st * 16 + mrow + r;
                    if (pl_ < TM) {
                        float val = fmaxf(fmaf(acc[s][n][r], sc_, sh_), 0.f);
                        const size_t o = ((size_t)simg * PLANE + (size_t)tile * TM + pl_) * CO + co;
                        if constexpr (OUTMODE == 1) {
                            u16 h, l; split_bf16(val, h, l);
                            yhi[o] = h; ylo[o] = l;
                        } else {
                            yf[o] = val;
                        }
                    }
                }
            }
        }
    }
}

// ---------------- legacy MFMA implicit-GEMM conv (L5: tiny plane) ----------------
template<int CI, int CO, int IH, int HILO_OUT>
__global__ __launch_bounds__(256) void conv_mfma(
    const u16* __restrict__ xhi, const u16* __restrict__ xlo,
    const u16* __restrict__ wB,
    const float* __restrict__ scale, const float* __restrict__ shift,
    float* __restrict__ yf, u16* __restrict__ yhi, u16* __restrict__ ylo,
    int M_total, int NB_N)
{
    constexpr int IW = IH, OH = IH - 2, OW = IH - 2, PLANE = OH * OW;
    constexpr int CIS = CI / 32;
    __shared__ __align__(16) u16 As[2 * 128 * 32];

    const int bid = blockIdx.x;
    const int nb  = bid % NB_N;
    const int mb  = bid / NB_N;
    const int ncg0 = nb * 8;
    const int t    = threadIdx.x;
    const int lane = t & 63;
    const int wv   = t >> 6;

    const int sp  = t >> 1;
    const int P_s = mb * 128 + sp;
    const int Pc  = (P_s < M_total) ? P_s : 0;
    const int simg = Pc / PLANE;
    const int sp2  = Pc - simg * PLANE;
    const int soh  = sp2 / OW;
    const int sow  = sp2 - soh * OW;
    const int sbase = (simg * IH + soh) * IW + sow;
    const int sh16  = (t & 1) << 4;
    const int swz   = (sp >> 1) & 3;
    char* Ab  = (char*)As;
    char* wA0 = Ab + sp * 64 + (((((t & 1) << 1)    ) ^ swz) << 4);
    char* wA1 = Ab + sp * 64 + (((((t & 1) << 1) | 1) ^ swz) << 4);

    const int pix0  = (wv << 5) + (lane & 15);
    const int roff0 = pix0 * 64 + (((lane >> 4) ^ ((pix0 >> 1) & 3)) << 4);

    f32x4 acc[2][8];
    #pragma unroll
    for (int i = 0; i < 2; ++i)
        #pragma unroll
        for (int j = 0; j < 8; ++j)
            #pragma unroll
            for (int r = 0; r < 4; ++r)
                acc[i][j][r] = 0.f;

    for (int tap = 0; tap < 9; ++tap) {
        const int koff = (tap / 3) * IW + (tap - (tap / 3) * 3);
        for (int cs = 0; cs < CIS; ++cs) {
            if (tap | cs) __syncthreads();
            {
                const int g = (sbase + koff) * CI + (cs << 5) + sh16;
                uint4 h0 = *(const uint4*)(xhi + g);
                uint4 h1 = *(const uint4*)(xhi + g + 8);
                uint4 l0 = *(const uint4*)(xlo + g);
                uint4 l1 = *(const uint4*)(xlo + g + 8);
                *(uint4*)(wA0)        = h0;
                *(uint4*)(wA1)        = h1;
                *(uint4*)(wA0 + 8192) = l0;
                *(uint4*)(wA1 + 8192) = l1;
            }
            __syncthreads();

            short8b bfr[8];
            #pragma unroll
            for (int n = 0; n < 8; ++n) {
                const u16* wp = wB + (((size_t)((ncg0 + n) * 9 + tap) * CIS + cs) << 9)
                                   + (lane << 3);
                bfr[n] = *(const short8b*)wp;
            }
            #pragma unroll
            for (int hl = 0; hl < 2; ++hl) {
                short8b a0 = *(const short8b*)(Ab + hl * 8192 + roff0);
                short8b a1 = *(const short8b*)(Ab + hl * 8192 + roff0 + 1024);
                #pragma unroll
                for (int n = 0; n < 8; ++n) {
                    acc[0][n] = __builtin_amdgcn_mfma_f32_16x16x32_bf16(a0, bfr[n], acc[0][n], 0, 0, 0);
                    acc[1][n] = __builtin_amdgcn_mfma_f32_16x16x32_bf16(a1, bfr[n], acc[1][n], 0, 0, 0);
                }
            }
        }
    }

    const int mrow = (lane >> 4) << 2;
    #pragma unroll
    for (int mt = 0; mt < 2; ++mt) {
        const int Pb = mb * 128 + ((wv * 2 + mt) << 4) + mrow;
        #pragma unroll
        for (int n = 0; n < 8; ++n) {
            const int co = ((ncg0 + n) << 4) + (lane & 15);
            const float sc_ = scale[co], sh_ = shift[co];
            #pragma unroll
            for (int r = 0; r < 4; ++r) {
                const int P = Pb + r;
                if (P < M_total) {
                    float val = fmaxf(fmaf(acc[mt][n][r], sc_, sh_), 0.f);
                    const size_t o = (size_t)P * CO + co;
                    if constexpr (HILO_OUT) {
                        u16 h, l; split_bf16(val, h, l);
                        yhi[o] = h; ylo[o] = l;
                    } else {
                        yf[o] = val;
                    }
                }
            }
        }
    }
}

// ---------------- split-K MFMA GEMM for FC layers ----------------
template<int N_REP>
__global__ __launch_bounds__(256) void fc_mfma_split(
    const u16* __restrict__ Ahi, const u16* __restrict__ Alo,
    const u16* __restrict__ wB, float* __restrict__ part,
    int M, int K, int NB_N, int KSC)
{
    __shared__ __align__(16) u16 As[2 * 128 * 32];
    const int KS = K >> 5;
    const int MB = M >> 7;
    const int Npad = NB_N * N_REP * 16;
    const int bid = blockIdx.x;
    const int nb  = bid % NB_N;
    int tmp = bid / NB_N;
    const int mb    = tmp % MB;
    const int split = tmp / MB;
    const int ks0 = split * KSC;
    const int ks1 = (ks0 + KSC < KS) ? (ks0 + KSC) : KS;
    const int ncg0 = nb * N_REP;
    const int t    = threadIdx.x;
    const int lane = t & 63;
    const int wv   = t >> 6;

    const int sp = t >> 1;
    int srow = mb * 128 + sp;
    if (srow >= M) srow = M - 1;
    const size_t abase = (size_t)srow * K + ((t & 1) << 4);
    const int swz = (sp >> 1) & 3;
    char* Ab  = (char*)As;
    char* wA0 = Ab + sp * 64 + (((((t & 1) << 1)    ) ^ swz) << 4);
    char* wA1 = Ab + sp * 64 + (((((t & 1) << 1) | 1) ^ swz) << 4);

    const int pix0  = (wv << 5) + (lane & 15);
    const int roff0 = pix0 * 64 + (((lane >> 4) ^ ((pix0 >> 1) & 3)) << 4);

    f32x4 acc[2][N_REP];
    #pragma unroll
    for (int i = 0; i < 2; ++i)
        #pragma unroll
        for (int j = 0; j < N_REP; ++j)
            #pragma unroll
            for (int r = 0; r < 4; ++r)
                acc[i][j][r] = 0.f;

    for (int ks = ks0; ks < ks1; ++ks) {
        if (ks != ks0) __syncthreads();
        {
            const size_t g = abase + ((size_t)ks << 5);
            uint4 h0 = *(const uint4*)(Ahi + g);
            uint4 h1 = *(const uint4*)(Ahi + g + 8);
            uint4 l0 = *(const uint4*)(Alo + g);
            uint4 l1 = *(const uint4*)(Alo + g + 8);
            *(uint4*)(wA0)        = h0;
            *(uint4*)(wA1)        = h1;
            *(uint4*)(wA0 + 8192) = l0;
            *(uint4*)(wA1 + 8192) = l1;
        }
        __syncthreads();

        short8b bfr[N_REP];
        #pragma unroll
        for (int n = 0; n < N_REP; ++n)
            bfr[n] = *(const short8b*)(wB + ((size_t)(ncg0 + n) * KS + ks) * 512
                                          + (lane << 3));
        #pragma unroll
        for (int hl = 0; hl < 2; ++hl) {
            short8b a0 = *(const short8b*)(Ab + hl * 8192 + roff0);
            short8b a1 = *(const short8b*)(Ab + hl * 8192 + roff0 + 1024);
            #pragma unroll
            for (int n = 0; n < N_REP; ++n) {
                acc[0][n] = __builtin_amdgcn_mfma_f32_16x16x32_bf16(a0, bfr[n], acc[0][n], 0, 0, 0);
                acc[1][n] = __builtin_amdgcn_mfma_f32_16x16x32_bf16(a1, bfr[n], acc[1][n], 0, 0, 0);
            }
        }
    }

    const int mrow = (lane >> 4) << 2;
    #pragma unroll
    for (int mt = 0; mt < 2; ++mt) {
        const int Pb = mb * 128 + ((wv * 2 + mt) << 4) + mrow;
        #pragma unroll
        for (int n = 0; n < N_REP; ++n) {
            const int co = ((ncg0 + n) << 4) + (lane & 15);
            #pragma unroll
            for (int r = 0; r < 4; ++r) {
                const int P = Pb + r;
                if (P < M)
                    part[((size_t)split * M + P) * Npad + co] = acc[mt][n][r];
            }
        }
    }
}

// reduce splits (fixed order -> deterministic), apply affine + relu, emit hi/lo or f32
template<int HILO_OUT>
__global__ void fc_reduce(const float* __restrict__ part, int nsplit,
                          const float* __restrict__ sc, const float* __restrict__ sh,
                          float* __restrict__ yf, u16* __restrict__ yhi,
                          u16* __restrict__ ylo,
                          int M, int Nact, int Npad, int relu)
{
    int idx = blockIdx.x * blockDim.x + threadIdx.x;
    if (idx >= M * Nact) return;
    int n = idx % Nact, m = idx / Nact;
    float s = 0.f;
    for (int k = 0; k < nsplit; ++k)
        s += part[((size_t)k * M + m) * Npad + n];
    float val = fmaf(s, sc ? sc[n] : 1.f, sh[n]);
    if (relu) val = fmaxf(val, 0.f);
    if constexpr (HILO_OUT) {
        u16 h, l; split_bf16(val, h, l);
        yhi[idx] = h; ylo[idx] = l;
    } else {
        yf[idx] = val;
    }
}

// ---------------- fp32 tiled conv (L1) ----------------
template<int CI, int CI_T, int IMGS, int NT, int IH, int CO, int HILO_OUT>
__global__ __launch_bounds__(NT) void conv_tiled(
    const float* __restrict__ x, const float* __restrict__ wst,
    const float* __restrict__ scale, const float* __restrict__ shift,
    float* __restrict__ y, u16* __restrict__ yhi, u16* __restrict__ ylo,
    int Btot)
{
    constexpr int IW = IH;
    constexpr int OH = IH - 2, OW = IW - 2;
    constexpr int PLANE  = OH * OW;
    constexpr int IPLANE = IH * IW;
    constexpr int NPIX = IMGS * PLANE;
    constexpr int LDSZ = IMGS * CI_T * IPLANE;
    constexpr int LDS4 = LDSZ / 4;
    constexpr int SLAB4 = CI_T * IPLANE / 4;
    constexpr int IMG_STRIDE4 = CI * IPLANE / 4;
    constexpr int NTILE = CI / CI_T;
    constexpr int NCG = CO / 16;
    constexpr int LOG2_NCG = (NCG == 8) ? 3 : ((NCG == 16) ? 4 : 5);
    static_assert(NPIX <= NT, "thread count too small");
    static_assert((CI_T * IPLANE) % 4 == 0 && (CI * IPLANE) % 4 == 0, "f4");

    __shared__ __align__(16) float xs[LDSZ];

    const int nim = (Btot + IMGS - 1) / IMGS;
    int n = blockIdx.x;
    int cg, ig;
    if ((nim & 7) == 0) {
        int xcd = n & 7;
        int w   = n >> 3;
        cg = w & (NCG - 1);
        ig = xcd + ((w >> LOG2_NCG) << 3);
    } else {
        cg = n & (NCG - 1);
        ig = n >> LOG2_NCG;
    }

    const int b0 = ig * IMGS;
    const int t  = threadIdx.x;

    const int tc  = (t < NPIX) ? t : (NPIX - 1);
    const int img = tc / PLANE;
    const int pix = tc - img * PLANE;
    const int oh  = pix / OW;
    const int ow  = pix - oh * OW;
    const bool act = (t < NPIX) && (b0 + img < Btot);

    float acc[16];
    #pragma unroll
    for (int q = 0; q < 16; ++q) acc[q] = 0.f;

    const int xbase = (img * CI_T * IH + oh) * IW + ow;

    for (int ct = 0; ct < NTILE; ++ct) {
        if (ct) __syncthreads();
        {
            const float4* xsrc = (const float4*)(x +
                ((long long)b0 * CI + (long long)ct * CI_T) * IPLANE);
            for (int j = t; j < LDS4; j += NT) {
                int im, r;
                if constexpr (IMGS == 1) { im = 0; r = j; }
                else { im = j / SLAB4; r = j - im * SLAB4; }
                float4 val = make_float4(0.f, 0.f, 0.f, 0.f);
                if (b0 + im < Btot) val = xsrc[(long long)im * IMG_STRIDE4 + r];
                ((float4*)xs)[j] = val;
            }
        }
        __syncthreads();
        const float* wt = wst + ((long long)(cg * CI + ct * CI_T) * 9) * 16;
        for (int ci = 0; ci < CI_T; ++ci) {
            const float* xr = xs + xbase + ci * IPLANE;
            const float* wr = wt + ci * 144;
            #pragma unroll
            for (int kh = 0; kh < 3; ++kh) {
                float x0 = xr[kh * IW + 0];
                float x1 = xr[kh * IW + 1];
                float x2 = xr[kh * IW + 2];
                const float* wk = wr + kh * 48;
                #pragma unroll
                for (int q = 0; q < 16; ++q) acc[q] = fmaf(x0, wk[q],      acc[q]);
                #pragma unroll
                for (int q = 0; q < 16; ++q) acc[q] = fmaf(x1, wk[16 + q], acc[q]);
                #pragma unroll
                for (int q = 0; q < 16; ++q) acc[q] = fmaf(x2, wk[32 + q], acc[q]);
            }
        }
    }

    if (act) {
        const int co0 = cg * 16;
        if constexpr (HILO_OUT) {
            const size_t o = ((size_t)(b0 + img) * PLANE + pix) * (size_t)CO + co0;
            u32* ohp = (u32*)(yhi + o);
            u32* olp = (u32*)(ylo + o);
            #pragma unroll
            for (int qq = 0; qq < 8; ++qq) {
                float v0 = fmaxf(fmaf(acc[2*qq],   scale[co0+2*qq],   shift[co0+2*qq]),   0.f);
                float v1 = fmaxf(fmaf(acc[2*qq+1], scale[co0+2*qq+1], shift[co0+2*qq+1]), 0.f);
                u16 h0, l0, h1, l1;
                split_bf16(v0, h0, l0); split_bf16(v1, h1, l1);
                ohp[qq] = (u32)h0 | ((u32)h1 << 16);
                olp[qq] = (u32)l0 | ((u32)l1 << 16);
            }
        } else {
            float* yp = y + ((long long)(b0 + img) * CO + co0) * PLANE + pix;
            #pragma unroll
            for (int q = 0; q < 16; ++q) {
                float val = fmaf(acc[q], scale[co0 + q], shift[co0 + q]);
                yp[(long long)q * PLANE] = fmaxf(val, 0.f);
            }
        }
    }
}

__global__ void softmax10_kernel(const float* __restrict__ logits,
                                 float* __restrict__ out, int B)
{
    int b = blockIdx.x * blockDim.x + threadIdx.x;
    if (b >= B) return;
    float l[10];
    float mx = -1e30f;
    #pragma unroll
    for (int i = 0; i < 10; ++i) { l[i] = logits[b * 10 + i]; mx = fmaxf(mx, l[i]); }
    float s = 0.f;
    #pragma unroll
    for (int i = 0; i < 10; ++i) { l[i] = __expf(l[i] - mx); s += l[i]; }
    float r = 1.f / s;
    #pragma unroll
    for (int i = 0; i < 10; ++i) out[b * 10 + i] = l[i] * r;
}

extern "C" void kernel_launch(void* const* d_in, const int* in_sizes, int n_in,
                              void* d_out, int out_size, void* d_ws, size_t ws_size,
                              hipStream_t stream)
{
    const int B = 512;
    const float* x = (const float*)d_in[0];
    auto W  = [&](int i) { return (const float*)d_in[1 + (i - 1) * 6 + 0]; };
    auto Bi = [&](int i) { return (const float*)d_in[1 + (i - 1) * 6 + 1]; };
    auto G  = [&](int i) { return (const float*)d_in[1 + (i - 1) * 6 + 2]; };
    auto Be = [&](int i) { return (const float*)d_in[1 + (i - 1) * 6 + 3]; };
    auto M  = [&](int i) { return (const float*)d_in[1 + (i - 1) * 6 + 4]; };
    auto V  = [&](int i) { return (const float*)d_in[1 + (i - 1) * 6 + 5]; };
    const float* fw1 = (const float*)d_in[37];
    const float* fb1 = (const float*)d_in[38];
    const float* fw2 = (const float*)d_in[39];
    const float* fb2 = (const float*)d_in[40];
    const float* fw3 = (const float*)d_in[41];
    const float* fb3 = (const float*)d_in[42];
    float* out = (float*)d_out;

    // ---- workspace layout (byte allocator, 256B aligned) ----
    char* pb = (char*)d_ws;
    auto takeB = [&](long long nb) { char* r = pb; pb += (nb + 255) & ~255LL; return r; };
    float* wst1 = (float*)takeB(128LL * 3 * 9 * 4);
    u16*   wB2  = (u16*)takeB(128LL * 128 * 9 * 2);
    u16*   wB3  = (u16*)takeB(256LL * 128 * 9 * 2);
    u16*   wB4  = (u16*)takeB(256LL * 256 * 9 * 2);
    u16*   wB5  = (u16*)takeB(512LL * 256 * 9 * 2);
    u16*   wB6  = (u16*)takeB(512LL * 4608 * 2);
    u16*   wF1  = (u16*)takeB(1024LL * 512 * 2);
    u16*   wF2  = (u16*)takeB(1024LL * 1024 * 2);
    u16*   wF3  = (u16*)takeB(16LL * 1024 * 2);
    const int COs[6] = {128, 128, 256, 256, 512, 512};
    float* SC[6]; float* SH[6];
    for (int i = 0; i < 6; ++i) {
        SC[i] = (float*)takeB(COs[i] * 4);
        SH[i] = (float*)takeB(COs[i] * 4);
    }
    // persistent full-batch buffers
    u16* a4hi = (u16*)takeB(512LL * 6400 * 2);   // L4 pooled out [512,25,256]
    u16* a4lo = (u16*)takeB(512LL * 6400 * 2);
    u16* y5hi = (u16*)takeB(512LL * 4608 * 2);
    u16* y5lo = (u16*)takeB(512LL * 4608 * 2);
    u16* t6hi = (u16*)takeB(512LL * 512 * 2);
    u16* t6lo = (u16*)takeB(512LL * 512 * 2);
    u16* f1hi = (u16*)takeB(512LL * 1024 * 2);
    u16* f1lo = (u16*)takeB(512LL * 1024 * 2);
    u16* f2hi = (u16*)takeB(512LL * 1024 * 2);
    u16* f2lo = (u16*)takeB(512LL * 1024 * 2);
    float* logits = (float*)takeB(512LL * 10 * 4);
    float* fcpart = (float*)takeB(16LL * 512 * 512 * 4);   // split-K partials (16.8 MB)
    long long wbytes = pb - (char*)d_ws;

    // per-image regions: A = max(a1 hi/lo 460800, a3 hi/lo 147456)
    //                    B = a2 hi/lo 100352
    const long long A_PER_B = 460800, B_PER_B = 100352;
    int Bc = B;
    while (Bc > 64 && wbytes + (long long)Bc * (A_PER_B + B_PER_B) > (long long)ws_size)
        Bc >>= 1;
    char* regionA = takeB((long long)Bc * A_PER_B);
    char* regionB = takeB((long long)Bc * B_PER_B);

    const int TB = 256;

    // ---- weight / bn prep ----
    prep_conv_w<<<cdiv(128LL * 3 * 9, TB), TB, 0, stream>>>(W(1), wst1, 128, 3);
    prep_wfrag<<<cdiv(128LL * 128 * 9, TB), TB, 0, stream>>>(W(2), wB2, 128, 128);
    prep_wfrag<<<cdiv(256LL * 128 * 9, TB), TB, 0, stream>>>(W(3), wB3, 256, 128);
    prep_wfrag<<<cdiv(256LL * 256 * 9, TB), TB, 0, stream>>>(W(4), wB4, 256, 256);
    prep_wfrag<<<cdiv(512LL * 256 * 9, TB), TB, 0, stream>>>(W(5), wB5, 512, 256);
    prep_gemm_wfrag<<<cdiv(512LL * 4608, TB), TB, 0, stream>>>(W(6), wB6, 512, 4608, 512, 1);
    prep_gemm_wfrag<<<cdiv(1024LL * 512, TB), TB, 0, stream>>>(fw1, wF1, 1024, 512, 1024, 0);
    prep_gemm_wfrag<<<cdiv(1024LL * 1024, TB), TB, 0, stream>>>(fw2, wF2, 1024, 1024, 1024, 0);
    prep_gemm_wfrag<<<cdiv(16LL * 1024, TB), TB, 0, stream>>>(fw3, wF3, 10, 1024, 16, 0);
    for (int i = 0; i < 6; ++i)
        bn_prep<<<cdiv(COs[i], TB), TB, 0, stream>>>(Bi(i + 1), G(i + 1), Be(i + 1),
                                                     M(i + 1), V(i + 1), SC[i], SH[i], COs[i]);

    for (int b0 = 0; b0 < B; b0 += Bc) {
        int bc = (B - b0 < Bc) ? (B - b0) : Bc;
        const float* xc = x + (long long)b0 * 3 * 32 * 32;

        // ping-pong: a1=A, a2=B, a3=A; a4 is persistent full-batch
        u16* a1hi = (u16*)regionA;                           // [bc,900,128]
        u16* a1lo = a1hi + (size_t)Bc * 115200;
        u16* a2hi = (u16*)regionB;                           // [bc,196,128] pooled
        u16* a2lo = a2hi + (size_t)Bc * 25088;
        u16* a3hi = (u16*)regionA;                           // [bc,144,256]
        u16* a3lo = a3hi + (size_t)Bc * 36864;

        // L1: fp32 conv -> NHWC bf16 hi/lo
        conv_tiled<3, 3, 1, 960, 32, 128, 1>
            <<<8 * bc, 960, 0, stream>>>(xc, wst1, SC[0], SH[0], nullptr, a1hi, a1lo, bc);

        // L2 + fused pool: TMR=4 (2 pooled rows), 7 band-tiles/img -> a2 hi/lo
        conv_mfma_halo<128, 128, 30, 4, 2, 2><<<bc * 7, 256, 0, stream>>>(
            a1hi, a1lo, wB2, SC[1], SH[1], nullptr, a2hi, a2lo);

        // L3: whole-plane tile (TMR=12, MSPW=3) -> a3 hi/lo
        conv_mfma_halo<128, 256, 14, 12, 3, 1><<<bc * 2, 256, 0, stream>>>(
            a2hi, a2lo, wB3, SC[2], SH[2], nullptr, a3hi, a3lo);

        // L4 + fused pool: whole-plane tile (10 rows -> 5 pooled) -> persistent a4
        conv_mfma_halo<256, 256, 12, 10, 2, 2><<<bc * 2, 256, 0, stream>>>(
            a3hi, a3lo, wB4, SC[3], SH[3], nullptr,
            a4hi + (size_t)b0 * 6400, a4lo + (size_t)b0 * 6400);
    }

    // L5: full batch, one launch. M=512*9=4608, grid 144 blocks.
    conv_mfma<256, 512, 5, 1><<<cdiv(512LL * 9, 128) * 4, 256, 0, stream>>>(
        a4hi, a4lo, wB5, SC[4], SH[4], nullptr, y5hi, y5lo, 512 * 9, 4);

    // ---- FC chain, full batch, split-K MFMA ----
    fc_mfma_split<8><<<256, 256, 0, stream>>>(y5hi, y5lo, wB6, fcpart, 512, 4608, 4, 9);
    fc_reduce<1><<<cdiv(512LL * 512, TB), TB, 0, stream>>>(
        fcpart, 16, SC[5], SH[5], nullptr, t6hi, t6lo, 512, 512, 512, 1);
    fc_mfma_split<8><<<256, 256, 0, stream>>>(t6hi, t6lo, wF1, fcpart, 512, 512, 8, 2);
    fc_reduce<1><<<cdiv(512LL * 1024, TB), TB, 0, stream>>>(
        fcpart, 8, nullptr, fb1, nullptr, f1hi, f1lo, 512, 1024, 1024, 1);
    fc_mfma_split<8><<<256, 256, 0, stream>>>(f1hi, f1lo, wF2, fcpart, 512, 1024, 8, 4);
    fc_reduce<1><<<cdiv(512LL * 1024, TB), TB, 0, stream>>>(
        fcpart, 8, nullptr, fb2, nullptr, f2hi, f2lo, 512, 1024, 1024, 1);
    fc_mfma_split<1><<<64, 256, 0, stream>>>(f2hi, f2lo, wF3, fcpart, 512, 1024, 1, 2);
    fc_reduce<0><<<cdiv(512LL * 10, TB), TB, 0, stream>>>(
        fcpart, 16, nullptr, fb3, logits, nullptr, nullptr, 512, 10, 16, 0);
    softmax10_kernel<<<cdiv(512LL, TB), TB, 0, stream>>>(logits, out, 512);
}

// Round 17
// 884.514 us; speedup vs baseline: 1.0600x; 1.0600x over previous
//
#include <hip/hip_runtime.h>
#include <math.h>

#define EPS 1e-5f

typedef unsigned short u16;
typedef unsigned int u32;
typedef __attribute__((ext_vector_type(8))) short short8b;   // 8 x bf16 bits
typedef __attribute__((ext_vector_type(4))) float f32x4;

static inline int cdiv(long long a, int b) { return (int)((a + b - 1) / b); }

__device__ __forceinline__ float sgnf(float w) {
    return (w > 0.f) ? 1.f : ((w < 0.f) ? -1.f : 0.f);
}

// round-to-nearest-even fp32 -> bf16 bits
__device__ __forceinline__ u16 bf16_rne(float v) {
    u32 u = __float_as_uint(v);
    return (u16)((u + 0x7FFFu + ((u >> 16) & 1u)) >> 16);
}
__device__ __forceinline__ void split_bf16(float v, u16& h, u16& l) {
    h = bf16_rne(v);
    float hf = __uint_as_float((u32)h << 16);
    l = bf16_rne(v - hf);
}

// ---------------- prep kernels ----------------

// fp32 path prep (L1): wst[co/16][ci][k][co%16] = sign(w[co][ci][k])
__global__ void prep_conv_w(const float* __restrict__ w, float* __restrict__ wst,
                            int CO, int CI)
{
    int idx = blockIdx.x * blockDim.x + threadIdx.x;
    int n = CO * CI * 9;
    if (idx >= n) return;
    int k  = idx % 9;
    int ci = (idx / 9) % CI;
    int co = idx / (9 * CI);
    wst[((((co >> 4) * CI + ci) * 9 + k) << 4) + (co & 15)] = sgnf(w[idx]);
}

// conv MFMA B-fragment prep: per (ncg,tap,cis) slab of 512 u16:
// [lane][j] = sign(w[co=ncg*16+(lane&15)][ci=cis*32+((lane>>4)&3)*8+j][tap]) as bf16
__global__ void prep_wfrag(const float* __restrict__ w, u16* __restrict__ wB,
                           int CO, int CI)
{
    int idx = blockIdx.x * blockDim.x + threadIdx.x;
    int n = CO * CI * 9;
    if (idx >= n) return;
    int tap = idx % 9;
    int ci  = (idx / 9) % CI;
    int co  = idx / (9 * CI);
    int CIS = CI >> 5;
    int ncg = co >> 4;
    int l   = (co & 15) | (((ci >> 3) & 3) << 4);
    int j   = ci & 7;
    int cis = ci >> 5;
    size_t off = (((size_t)(ncg * 9 + tap) * CIS + cis) * 64 + l) * 8 + j;
    float wv = w[idx];
    wB[off] = wv > 0.f ? (u16)0x3F80 : (wv < 0.f ? (u16)0xBF80 : (u16)0);
}

// GEMM B-fragment prep for FC layers. logical W[o][k], o padded to OUTP.
// mode 0: src = w[o*K + k]. mode 1 (L6, NHWC features): k = tap*512 + ci,
// src = w[(o*512 + ci)*9 + tap].
__global__ void prep_gemm_wfrag(const float* __restrict__ w, u16* __restrict__ frag,
                                int OUT, int K, int OUTP, int mode)
{
    long long idx = (long long)blockIdx.x * blockDim.x + threadIdx.x;
    long long n = (long long)OUTP * K;
    if (idx >= n) return;
    int k = (int)(idx % K);
    int o = (int)(idx / K);
    u16 b = 0;
    if (o < OUT) {
        float wv;
        if (mode == 1) {
            int ci = k & 511, tap = k >> 9;
            wv = w[((size_t)o * 512 + ci) * 9 + tap];
        } else {
            wv = w[(size_t)o * K + k];
        }
        b = wv > 0.f ? (u16)0x3F80 : (wv < 0.f ? (u16)0xBF80 : (u16)0);
    }
    int KS = K >> 5;
    int ncg = o >> 4;
    int lane = (o & 15) | (((k >> 3) & 3) << 4);
    int j = k & 7, ks = k >> 5;
    frag[((size_t)(ncg * KS + ks) * 64 + lane) * 8 + j] = b;
}

__global__ void bn_prep(const float* __restrict__ bias, const float* __restrict__ g,
                        const float* __restrict__ be, const float* __restrict__ m,
                        const float* __restrict__ v,
                        float* __restrict__ sc, float* __restrict__ sh, int CO)
{
    int i = blockIdx.x * blockDim.x + threadIdx.x;
    if (i >= CO) return;
    float s = g[i] * rsqrtf(v[i] + EPS);
    sc[i] = s;
    sh[i] = be[i] - m[i] * s + bias[i] * s;
}

// ---------------- halo-staged MFMA conv + bn + relu (+ fused 2x2 pool) ------
// R10/R15 structure (best measured): sync reg-staged, single LDS buffer,
// two barriers per ci-slab. Block = 256 thr / 4 waves owns a TMR-row
// full-width band of ONE image and up to 8 co-tiles.
// Design notes from the staging-matrix exploration (R8-R16):
//  - async-reg staging spills (R8/R12); gload_lds drains at the barrier
//    (R11) or kills occupancy via dbuf VGPR+LDS (R13); one-barrier dbuf
//    halves barriers but the 2x LDS occupancy loss dominates (R16).
//  - do NOT shrink TMR/MSPW for occupancy: B-fragment loads amortize over
//    MSPW (R9/R14); these layers are per-MFMA-overhead bound.
// OUTMODE: 0 = f32 NHWC, 1 = hi/lo NHWC, 2 = fused 2x2 maxpool -> hi/lo NHWC.
template<int CI, int CO, int IH, int TMR, int MSPW, int OUTMODE>
__global__ __launch_bounds__(256) void conv_mfma_halo(
    const u16* __restrict__ xhi, const u16* __restrict__ xlo,
    const u16* __restrict__ wB,
    const float* __restrict__ scale, const float* __restrict__ shift,
    float* __restrict__ yf, u16* __restrict__ yhi, u16* __restrict__ ylo)
{
    constexpr int IW = IH, OH = IH - 2, OW = OH, PLANE = OH * OW, IPLANE = IH * IW;
    constexpr int TM = TMR * OW;            // output px per tile
    constexpr int TILES = PLANE / TM;
    static_assert(PLANE % TM == 0, "tile");
    constexpr int PX = (TMR + 2) * IW;      // staged px per slab
    constexpr int CIS = CI / 32;
    constexpr int NSUB = (TM + 15) / 16;
    static_assert(NSUB <= 4 * MSPW, "slots");
    static_assert(OUTMODE != 2 || (TMR % 2 == 0 && OW % 2 == 0), "pool");
    constexpr int NBN = CO / 128;           // n-blocks (8 co-tiles each)
    constexpr int PLB = PX * 64;            // bytes per hi/lo plane in LDS
    constexpr int PWT = OW / 2;             // pooled width
    constexpr int NQ  = (TMR / 2) * PWT;    // pool windows per tile
    constexpr int PPLANE = (OH / 2) * (OW / 2);

    __shared__ __align__(16) u16 As[2 * PX * 32];

    const int gid  = blockIdx.x;
    const int nb   = gid % NBN;
    const int tw   = gid / NBN;
    const int simg = tw / TILES;
    const int tile = tw - simg * TILES;
    const int ncg0 = nb * 8;
    const int t = threadIdx.x, lane = t & 63, wv = t >> 6;
    const long long gpix0 = (long long)simg * IPLANE + (long long)tile * TMR * IW;

    // per-slot LDS pixel base (window-local), clamped; m->px mapping
    int lpb[MSPW];
    #pragma unroll
    for (int s = 0; s < MSPW; ++s) {
        int st = wv * MSPW + s;
        int m = st * 16 + (lane & 15);
        if constexpr (OUTMODE == 2) {
            int q = m >> 2, r = m & 3;
            if (q > NQ - 1) q = NQ - 1;
            int pr = q / PWT, pc = q - pr * PWT;
            lpb[s] = (2 * pr + (r >> 1)) * IW + 2 * pc + (r & 1);
        } else {
            int p = (m > TM - 1) ? (TM - 1) : m;
            int pr = p / OW, pc = p - pr * OW;
            lpb[s] = pr * IW + pc;
        }
    }

    f32x4 acc[MSPW][8];
    #pragma unroll
    for (int s = 0; s < MSPW; ++s)
        #pragma unroll
        for (int n = 0; n < 8; ++n)
            #pragma unroll
            for (int r = 0; r < 4; ++r)
                acc[s][n][r] = 0.f;

    for (int cs = 0; cs < CIS; ++cs) {
        if (cs) __syncthreads();
        // ---- stage halo patch once (hi + lo), coalesced, swizzled ----
        for (int u = t; u < PX * 8; u += 256) {
            int lp = u >> 3, sub = u & 7, pl = sub >> 2, cib = sub & 3;
            const u16* sp = pl ? xlo : xhi;
            uint4 v = *(const uint4*)(sp + (gpix0 + lp) * CI + (cs << 5) + (cib << 3));
            *(uint4*)((char*)As + pl * PLB + lp * 64 + ((cib ^ ((lp >> 1) & 3)) << 4)) = v;
        }
        __syncthreads();
        // ---- sweep 9 taps from LDS ----
        #pragma unroll
        for (int tap = 0; tap < 9; ++tap) {
            const int kh = tap / 3, kw = tap - 3 * (tap / 3);
            short8b bfr[8];
            #pragma unroll
            for (int n = 0; n < 8; ++n)
                bfr[n] = *(const short8b*)(wB +
                    (((size_t)((ncg0 + n) * 9 + tap) * CIS + cs) << 9) + (lane << 3));
            #pragma unroll
            for (int s = 0; s < MSPW; ++s) {
                const int lp  = lpb[s] + kh * IW + kw;
                const int off = lp * 64 + (((lane >> 4) ^ ((lp >> 1) & 3)) << 4);
                short8b ah = *(const short8b*)((char*)As + off);
                short8b al = *(const short8b*)((char*)As + PLB + off);
                #pragma unroll
                for (int n = 0; n < 8; ++n) {
                    acc[s][n] = __builtin_amdgcn_mfma_f32_16x16x32_bf16(ah, bfr[n], acc[s][n], 0, 0, 0);
                    acc[s][n] = __builtin_amdgcn_mfma_f32_16x16x32_bf16(al, bfr[n], acc[s][n], 0, 0, 0);
                }
            }
        }
    }

    // ---- epilogue (C/D mapping: col=lane&15 -> co, row=(lane>>4)*4+r -> m) ----
    const int mrow = (lane >> 4) << 2;
    #pragma unroll
    for (int s = 0; s < MSPW; ++s) {
        const int st = wv * MSPW + s;
        if constexpr (OUTMODE == 2) {
            // lane holds m = st*16 + mrow + (0..3) = window q = st*4 + (lane>>4)
            int q = st * 4 + (lane >> 4);
            if (q > NQ - 1) q = NQ - 1;
            const int pr = q / PWT, pc = q - pr * PWT;
            const int gq = (tile * (TMR / 2) + pr) * PWT + pc;
            #pragma unroll
            for (int n = 0; n < 8; ++n) {
                const int co = ((ncg0 + n) << 4) + (lane & 15);
                const float sc_ = scale[co], sh_ = shift[co];
                float vmax = 0.f;   // relu'd values are >= 0
                #pragma unroll
                for (int r = 0; r < 4; ++r) {
                    float val = fmaxf(fmaf(acc[s][n][r], sc_, sh_), 0.f);
                    vmax = fmaxf(vmax, val);
                }
                const size_t o = ((size_t)simg * PPLANE + gq) * CO + co;
                u16 h, l; split_bf16(vmax, h, l);
                yhi[o] = h; ylo[o] = l;   // duplicate lanes write identical bytes
            }
        } else {
            #pragma unroll
            for (int n = 0; n < 8; ++n) {
                const int co = ((ncg0 + n) << 4) + (lane & 15);
                const float sc_ = scale[co], sh_ = shift[co];
                #pragma unroll
                for (int r = 0; r < 4; ++r) {
                    const int pl_ = st * 16 + mrow + r;
                    if (pl_ < TM) {
                        float val = fmaxf(fmaf(acc[s][n][r], sc_, sh_), 0.f);
                        const size_t o = ((size_t)simg * PLANE + (size_t)tile * TM + pl_) * CO + co;
                        if constexpr (OUTMODE == 1) {
                            u16 h, l; split_bf16(val, h, l);
                            yhi[o] = h; ylo[o] = l;
                        } else {
                            yf[o] = val;
                        }
                    }
                }
            }
        }
    }
}

// ---------------- legacy MFMA implicit-GEMM conv (L5: tiny plane) ----------------
template<int CI, int CO, int IH, int HILO_OUT>
__global__ __launch_bounds__(256) void conv_mfma(
    const u16* __restrict__ xhi, const u16* __restrict__ xlo,
    const u16* __restrict__ wB,
    const float* __restrict__ scale, const float* __restrict__ shift,
    float* __restrict__ yf, u16* __restrict__ yhi, u16* __restrict__ ylo,
    int M_total, int NB_N)
{
    constexpr int IW = IH, OH = IH - 2, OW = IH - 2, PLANE = OH * OW;
    constexpr int CIS = CI / 32;
    __shared__ __align__(16) u16 As[2 * 128 * 32];

    const int bid = blockIdx.x;
    const int nb  = bid % NB_N;
    const int mb  = bid / NB_N;
    const int ncg0 = nb * 8;
    const int t    = threadIdx.x;
    const int lane = t & 63;
    const int wv   = t >> 6;

    const int sp  = t >> 1;
    const int P_s = mb * 128 + sp;
    const int Pc  = (P_s < M_total) ? P_s : 0;
    const int simg = Pc / PLANE;
    const int sp2  = Pc - simg * PLANE;
    const int soh  = sp2 / OW;
    const int sow  = sp2 - soh * OW;
    const int sbase = (simg * IH + soh) * IW + sow;
    const int sh16  = (t & 1) << 4;
    const int swz   = (sp >> 1) & 3;
    char* Ab  = (char*)As;
    char* wA0 = Ab + sp * 64 + (((((t & 1) << 1)    ) ^ swz) << 4);
    char* wA1 = Ab + sp * 64 + (((((t & 1) << 1) | 1) ^ swz) << 4);

    const int pix0  = (wv << 5) + (lane & 15);
    const int roff0 = pix0 * 64 + (((lane >> 4) ^ ((pix0 >> 1) & 3)) << 4);

    f32x4 acc[2][8];
    #pragma unroll
    for (int i = 0; i < 2; ++i)
        #pragma unroll
        for (int j = 0; j < 8; ++j)
            #pragma unroll
            for (int r = 0; r < 4; ++r)
                acc[i][j][r] = 0.f;

    for (int tap = 0; tap < 9; ++tap) {
        const int koff = (tap / 3) * IW + (tap - (tap / 3) * 3);
        for (int cs = 0; cs < CIS; ++cs) {
            if (tap | cs) __syncthreads();
            {
                const int g = (sbase + koff) * CI + (cs << 5) + sh16;
                uint4 h0 = *(const uint4*)(xhi + g);
                uint4 h1 = *(const uint4*)(xhi + g + 8);
                uint4 l0 = *(const uint4*)(xlo + g);
                uint4 l1 = *(const uint4*)(xlo + g + 8);
                *(uint4*)(wA0)        = h0;
                *(uint4*)(wA1)        = h1;
                *(uint4*)(wA0 + 8192) = l0;
                *(uint4*)(wA1 + 8192) = l1;
            }
            __syncthreads();

            short8b bfr[8];
            #pragma unroll
            for (int n = 0; n < 8; ++n) {
                const u16* wp = wB + (((size_t)((ncg0 + n) * 9 + tap) * CIS + cs) << 9)
                                   + (lane << 3);
                bfr[n] = *(const short8b*)wp;
            }
            #pragma unroll
            for (int hl = 0; hl < 2; ++hl) {
                short8b a0 = *(const short8b*)(Ab + hl * 8192 + roff0);
                short8b a1 = *(const short8b*)(Ab + hl * 8192 + roff0 + 1024);
                #pragma unroll
                for (int n = 0; n < 8; ++n) {
                    acc[0][n] = __builtin_amdgcn_mfma_f32_16x16x32_bf16(a0, bfr[n], acc[0][n], 0, 0, 0);
                    acc[1][n] = __builtin_amdgcn_mfma_f32_16x16x32_bf16(a1, bfr[n], acc[1][n], 0, 0, 0);
                }
            }
        }
    }

    const int mrow = (lane >> 4) << 2;
    #pragma unroll
    for (int mt = 0; mt < 2; ++mt) {
        const int Pb = mb * 128 + ((wv * 2 + mt) << 4) + mrow;
        #pragma unroll
        for (int n = 0; n < 8; ++n) {
            const int co = ((ncg0 + n) << 4) + (lane & 15);
            const float sc_ = scale[co], sh_ = shift[co];
            #pragma unroll
            for (int r = 0; r < 4; ++r) {
                const int P = Pb + r;
                if (P < M_total) {
                    float val = fmaxf(fmaf(acc[mt][n][r], sc_, sh_), 0.f);
                    const size_t o = (size_t)P * CO + co;
                    if constexpr (HILO_OUT) {
                        u16 h, l; split_bf16(val, h, l);
                        yhi[o] = h; ylo[o] = l;
                    } else {
                        yf[o] = val;
                    }
                }
            }
        }
    }
}

// ---------------- split-K MFMA GEMM for FC layers ----------------
template<int N_REP>
__global__ __launch_bounds__(256) void fc_mfma_split(
    const u16* __restrict__ Ahi, const u16* __restrict__ Alo,
    const u16* __restrict__ wB, float* __restrict__ part,
    int M, int K, int NB_N, int KSC)
{
    __shared__ __align__(16) u16 As[2 * 128 * 32];
    const int KS = K >> 5;
    const int MB = M >> 7;
    const int Npad = NB_N * N_REP * 16;
    const int bid = blockIdx.x;
    const int nb  = bid % NB_N;
    int tmp = bid / NB_N;
    const int mb    = tmp % MB;
    const int split = tmp / MB;
    const int ks0 = split * KSC;
    const int ks1 = (ks0 + KSC < KS) ? (ks0 + KSC) : KS;
    const int ncg0 = nb * N_REP;
    const int t    = threadIdx.x;
    const int lane = t & 63;
    const int wv   = t >> 6;

    const int sp = t >> 1;
    int srow = mb * 128 + sp;
    if (srow >= M) srow = M - 1;
    const size_t abase = (size_t)srow * K + ((t & 1) << 4);
    const int swz = (sp >> 1) & 3;
    char* Ab  = (char*)As;
    char* wA0 = Ab + sp * 64 + (((((t & 1) << 1)    ) ^ swz) << 4);
    char* wA1 = Ab + sp * 64 + (((((t & 1) << 1) | 1) ^ swz) << 4);

    const int pix0  = (wv << 5) + (lane & 15);
    const int roff0 = pix0 * 64 + (((lane >> 4) ^ ((pix0 >> 1) & 3)) << 4);

    f32x4 acc[2][N_REP];
    #pragma unroll
    for (int i = 0; i < 2; ++i)
        #pragma unroll
        for (int j = 0; j < N_REP; ++j)
            #pragma unroll
            for (int r = 0; r < 4; ++r)
                acc[i][j][r] = 0.f;

    for (int ks = ks0; ks < ks1; ++ks) {
        if (ks != ks0) __syncthreads();
        {
            const size_t g = abase + ((size_t)ks << 5);
            uint4 h0 = *(const uint4*)(Ahi + g);
            uint4 h1 = *(const uint4*)(Ahi + g + 8);
            uint4 l0 = *(const uint4*)(Alo + g);
            uint4 l1 = *(const uint4*)(Alo + g + 8);
            *(uint4*)(wA0)        = h0;
            *(uint4*)(wA1)        = h1;
            *(uint4*)(wA0 + 8192) = l0;
            *(uint4*)(wA1 + 8192) = l1;
        }
        __syncthreads();

        short8b bfr[N_REP];
        #pragma unroll
        for (int n = 0; n < N_REP; ++n)
            bfr[n] = *(const short8b*)(wB + ((size_t)(ncg0 + n) * KS + ks) * 512
                                          + (lane << 3));
        #pragma unroll
        for (int hl = 0; hl < 2; ++hl) {
            short8b a0 = *(const short8b*)(Ab + hl * 8192 + roff0);
            short8b a1 = *(const short8b*)(Ab + hl * 8192 + roff0 + 1024);
            #pragma unroll
            for (int n = 0; n < N_REP; ++n) {
                acc[0][n] = __builtin_amdgcn_mfma_f32_16x16x32_bf16(a0, bfr[n], acc[0][n], 0, 0, 0);
                acc[1][n] = __builtin_amdgcn_mfma_f32_16x16x32_bf16(a1, bfr[n], acc[1][n], 0, 0, 0);
            }
        }
    }

    const int mrow = (lane >> 4) << 2;
    #pragma unroll
    for (int mt = 0; mt < 2; ++mt) {
        const int Pb = mb * 128 + ((wv * 2 + mt) << 4) + mrow;
        #pragma unroll
        for (int n = 0; n < N_REP; ++n) {
            const int co = ((ncg0 + n) << 4) + (lane & 15);
            #pragma unroll
            for (int r = 0; r < 4; ++r) {
                const int P = Pb + r;
                if (P < M)
                    part[((size_t)split * M + P) * Npad + co] = acc[mt][n][r];
            }
        }
    }
}

// reduce splits (fixed order -> deterministic), apply affine + relu, emit hi/lo or f32
template<int HILO_OUT>
__global__ void fc_reduce(const float* __restrict__ part, int nsplit,
                          const float* __restrict__ sc, const float* __restrict__ sh,
                          float* __restrict__ yf, u16* __restrict__ yhi,
                          u16* __restrict__ ylo,
                          int M, int Nact, int Npad, int relu)
{
    int idx = blockIdx.x * blockDim.x + threadIdx.x;
    if (idx >= M * Nact) return;
    int n = idx % Nact, m = idx / Nact;
    float s = 0.f;
    for (int k = 0; k < nsplit; ++k)
        s += part[((size_t)k * M + m) * Npad + n];
    float val = fmaf(s, sc ? sc[n] : 1.f, sh[n]);
    if (relu) val = fmaxf(val, 0.f);
    if constexpr (HILO_OUT) {
        u16 h, l; split_bf16(val, h, l);
        yhi[idx] = h; ylo[idx] = l;
    } else {
        yf[idx] = val;
    }
}

// ---------------- fp32 tiled conv (L1) ----------------
template<int CI, int CI_T, int IMGS, int NT, int IH, int CO, int HILO_OUT>
__global__ __launch_bounds__(NT) void conv_tiled(
    const float* __restrict__ x, const float* __restrict__ wst,
    const float* __restrict__ scale, const float* __restrict__ shift,
    float* __restrict__ y, u16* __restrict__ yhi, u16* __restrict__ ylo,
    int Btot)
{
    constexpr int IW = IH;
    constexpr int OH = IH - 2, OW = IW - 2;
    constexpr int PLANE  = OH * OW;
    constexpr int IPLANE = IH * IW;
    constexpr int NPIX = IMGS * PLANE;
    constexpr int LDSZ = IMGS * CI_T * IPLANE;
    constexpr int LDS4 = LDSZ / 4;
    constexpr int SLAB4 = CI_T * IPLANE / 4;
    constexpr int IMG_STRIDE4 = CI * IPLANE / 4;
    constexpr int NTILE = CI / CI_T;
    constexpr int NCG = CO / 16;
    constexpr int LOG2_NCG = (NCG == 8) ? 3 : ((NCG == 16) ? 4 : 5);
    static_assert(NPIX <= NT, "thread count too small");
    static_assert((CI_T * IPLANE) % 4 == 0 && (CI * IPLANE) % 4 == 0, "f4");

    __shared__ __align__(16) float xs[LDSZ];

    const int nim = (Btot + IMGS - 1) / IMGS;
    int n = blockIdx.x;
    int cg, ig;
    if ((nim & 7) == 0) {
        int xcd = n & 7;
        int w   = n >> 3;
        cg = w & (NCG - 1);
        ig = xcd + ((w >> LOG2_NCG) << 3);
    } else {
        cg = n & (NCG - 1);
        ig = n >> LOG2_NCG;
    }

    const int b0 = ig * IMGS;
    const int t  = threadIdx.x;

    const int tc  = (t < NPIX) ? t : (NPIX - 1);
    const int img = tc / PLANE;
    const int pix = tc - img * PLANE;
    const int oh  = pix / OW;
    const int ow  = pix - oh * OW;
    const bool act = (t < NPIX) && (b0 + img < Btot);

    float acc[16];
    #pragma unroll
    for (int q = 0; q < 16; ++q) acc[q] = 0.f;

    const int xbase = (img * CI_T * IH + oh) * IW + ow;

    for (int ct = 0; ct < NTILE; ++ct) {
        if (ct) __syncthreads();
        {
            const float4* xsrc = (const float4*)(x +
                ((long long)b0 * CI + (long long)ct * CI_T) * IPLANE);
            for (int j = t; j < LDS4; j += NT) {
                int im, r;
                if constexpr (IMGS == 1) { im = 0; r = j; }
                else { im = j / SLAB4; r = j - im * SLAB4; }
                float4 val = make_float4(0.f, 0.f, 0.f, 0.f);
                if (b0 + im < Btot) val = xsrc[(long long)im * IMG_STRIDE4 + r];
                ((float4*)xs)[j] = val;
            }
        }
        __syncthreads();
        const float* wt = wst + ((long long)(cg * CI + ct * CI_T) * 9) * 16;
        for (int ci = 0; ci < CI_T; ++ci) {
            const float* xr = xs + xbase + ci * IPLANE;
            const float* wr = wt + ci * 144;
            #pragma unroll
            for (int kh = 0; kh < 3; ++kh) {
                float x0 = xr[kh * IW + 0];
                float x1 = xr[kh * IW + 1];
                float x2 = xr[kh * IW + 2];
                const float* wk = wr + kh * 48;
                #pragma unroll
                for (int q = 0; q < 16; ++q) acc[q] = fmaf(x0, wk[q],      acc[q]);
                #pragma unroll
                for (int q = 0; q < 16; ++q) acc[q] = fmaf(x1, wk[16 + q], acc[q]);
                #pragma unroll
                for (int q = 0; q < 16; ++q) acc[q] = fmaf(x2, wk[32 + q], acc[q]);
            }
        }
    }

    if (act) {
        const int co0 = cg * 16;
        if constexpr (HILO_OUT) {
            const size_t o = ((size_t)(b0 + img) * PLANE + pix) * (size_t)CO + co0;
            u32* ohp = (u32*)(yhi + o);
            u32* olp = (u32*)(ylo + o);
            #pragma unroll
            for (int qq = 0; qq < 8; ++qq) {
                float v0 = fmaxf(fmaf(acc[2*qq],   scale[co0+2*qq],   shift[co0+2*qq]),   0.f);
                float v1 = fmaxf(fmaf(acc[2*qq+1], scale[co0+2*qq+1], shift[co0+2*qq+1]), 0.f);
                u16 h0, l0, h1, l1;
                split_bf16(v0, h0, l0); split_bf16(v1, h1, l1);
                ohp[qq] = (u32)h0 | ((u32)h1 << 16);
                olp[qq] = (u32)l0 | ((u32)l1 << 16);
            }
        } else {
            float* yp = y + ((long long)(b0 + img) * CO + co0) * PLANE + pix;
            #pragma unroll
            for (int q = 0; q < 16; ++q) {
                float val = fmaf(acc[q], scale[co0 + q], shift[co0 + q]);
                yp[(long long)q * PLANE] = fmaxf(val, 0.f);
            }
        }
    }
}

__global__ void softmax10_kernel(const float* __restrict__ logits,
                                 float* __restrict__ out, int B)
{
    int b = blockIdx.x * blockDim.x + threadIdx.x;
    if (b >= B) return;
    float l[10];
    float mx = -1e30f;
    #pragma unroll
    for (int i = 0; i < 10; ++i) { l[i] = logits[b * 10 + i]; mx = fmaxf(mx, l[i]); }
    float s = 0.f;
    #pragma unroll
    for (int i = 0; i < 10; ++i) { l[i] = __expf(l[i] - mx); s += l[i]; }
    float r = 1.f / s;
    #pragma unroll
    for (int i = 0; i < 10; ++i) out[b * 10 + i] = l[i] * r;
}

extern "C" void kernel_launch(void* const* d_in, const int* in_sizes, int n_in,
                              void* d_out, int out_size, void* d_ws, size_t ws_size,
                              hipStream_t stream)
{
    const int B = 512;
    const float* x = (const float*)d_in[0];
    auto W  = [&](int i) { return (const float*)d_in[1 + (i - 1) * 6 + 0]; };
    auto Bi = [&](int i) { return (const float*)d_in[1 + (i - 1) * 6 + 1]; };
    auto G  = [&](int i) { return (const float*)d_in[1 + (i - 1) * 6 + 2]; };
    auto Be = [&](int i) { return (const float*)d_in[1 + (i - 1) * 6 + 3]; };
    auto M  = [&](int i) { return (const float*)d_in[1 + (i - 1) * 6 + 4]; };
    auto V  = [&](int i) { return (const float*)d_in[1 + (i - 1) * 6 + 5]; };
    const float* fw1 = (const float*)d_in[37];
    const float* fb1 = (const float*)d_in[38];
    const float* fw2 = (const float*)d_in[39];
    const float* fb2 = (const float*)d_in[40];
    const float* fw3 = (const float*)d_in[41];
    const float* fb3 = (const float*)d_in[42];
    float* out = (float*)d_out;

    // ---- workspace layout (byte allocator, 256B aligned) ----
    char* pb = (char*)d_ws;
    auto takeB = [&](long long nb) { char* r = pb; pb += (nb + 255) & ~255LL; return r; };
    float* wst1 = (float*)takeB(128LL * 3 * 9 * 4);
    u16*   wB2  = (u16*)takeB(128LL * 128 * 9 * 2);
    u16*   wB3  = (u16*)takeB(256LL * 128 * 9 * 2);
    u16*   wB4  = (u16*)takeB(256LL * 256 * 9 * 2);
    u16*   wB5  = (u16*)takeB(512LL * 256 * 9 * 2);
    u16*   wB6  = (u16*)takeB(512LL * 4608 * 2);
    u16*   wF1  = (u16*)takeB(1024LL * 512 * 2);
    u16*   wF2  = (u16*)takeB(1024LL * 1024 * 2);
    u16*   wF3  = (u16*)takeB(16LL * 1024 * 2);
    const int COs[6] = {128, 128, 256, 256, 512, 512};
    float* SC[6]; float* SH[6];
    for (int i = 0; i < 6; ++i) {
        SC[i] = (float*)takeB(COs[i] * 4);
        SH[i] = (float*)takeB(COs[i] * 4);
    }
    // persistent full-batch buffers
    u16* a4hi = (u16*)takeB(512LL * 6400 * 2);   // L4 pooled out [512,25,256]
    u16* a4lo = (u16*)takeB(512LL * 6400 * 2);
    u16* y5hi = (u16*)takeB(512LL * 4608 * 2);
    u16* y5lo = (u16*)takeB(512LL * 4608 * 2);
    u16* t6hi = (u16*)takeB(512LL * 512 * 2);
    u16* t6lo = (u16*)takeB(512LL * 512 * 2);
    u16* f1hi = (u16*)takeB(512LL * 1024 * 2);
    u16* f1lo = (u16*)takeB(512LL * 1024 * 2);
    u16* f2hi = (u16*)takeB(512LL * 1024 * 2);
    u16* f2lo = (u16*)takeB(512LL * 1024 * 2);
    float* logits = (float*)takeB(512LL * 10 * 4);
    float* fcpart = (float*)takeB(16LL * 512 * 512 * 4);   // split-K partials (16.8 MB)
    long long wbytes = pb - (char*)d_ws;

    // per-image regions: A = max(a1 hi/lo 460800, a3 hi/lo 147456)
    //                    B = a2 hi/lo 100352
    const long long A_PER_B = 460800, B_PER_B = 100352;
    int Bc = B;
    while (Bc > 64 && wbytes + (long long)Bc * (A_PER_B + B_PER_B) > (long long)ws_size)
        Bc >>= 1;
    char* regionA = takeB((long long)Bc * A_PER_B);
    char* regionB = takeB((long long)Bc * B_PER_B);

    const int TB = 256;

    // ---- weight / bn prep ----
    prep_conv_w<<<cdiv(128LL * 3 * 9, TB), TB, 0, stream>>>(W(1), wst1, 128, 3);
    prep_wfrag<<<cdiv(128LL * 128 * 9, TB), TB, 0, stream>>>(W(2), wB2, 128, 128);
    prep_wfrag<<<cdiv(256LL * 128 * 9, TB), TB, 0, stream>>>(W(3), wB3, 256, 128);
    prep_wfrag<<<cdiv(256LL * 256 * 9, TB), TB, 0, stream>>>(W(4), wB4, 256, 256);
    prep_wfrag<<<cdiv(512LL * 256 * 9, TB), TB, 0, stream>>>(W(5), wB5, 512, 256);
    prep_gemm_wfrag<<<cdiv(512LL * 4608, TB), TB, 0, stream>>>(W(6), wB6, 512, 4608, 512, 1);
    prep_gemm_wfrag<<<cdiv(1024LL * 512, TB), TB, 0, stream>>>(fw1, wF1, 1024, 512, 1024, 0);
    prep_gemm_wfrag<<<cdiv(1024LL * 1024, TB), TB, 0, stream>>>(fw2, wF2, 1024, 1024, 1024, 0);
    prep_gemm_wfrag<<<cdiv(16LL * 1024, TB), TB, 0, stream>>>(fw3, wF3, 10, 1024, 16, 0);
    for (int i = 0; i < 6; ++i)
        bn_prep<<<cdiv(COs[i], TB), TB, 0, stream>>>(Bi(i + 1), G(i + 1), Be(i + 1),
                                                     M(i + 1), V(i + 1), SC[i], SH[i], COs[i]);

    for (int b0 = 0; b0 < B; b0 += Bc) {
        int bc = (B - b0 < Bc) ? (B - b0) : Bc;
        const float* xc = x + (long long)b0 * 3 * 32 * 32;

        // ping-pong: a1=A, a2=B, a3=A; a4 is persistent full-batch
        u16* a1hi = (u16*)regionA;                           // [bc,900,128]
        u16* a1lo = a1hi + (size_t)Bc * 115200;
        u16* a2hi = (u16*)regionB;                           // [bc,196,128] pooled
        u16* a2lo = a2hi + (size_t)Bc * 25088;
        u16* a3hi = (u16*)regionA;                           // [bc,144,256]
        u16* a3lo = a3hi + (size_t)Bc * 36864;

        // L1: fp32 conv -> NHWC bf16 hi/lo
        conv_tiled<3, 3, 1, 960, 32, 128, 1>
            <<<8 * bc, 960, 0, stream>>>(xc, wst1, SC[0], SH[0], nullptr, a1hi, a1lo, bc);

        // L2 + fused pool: TMR=4 (2 pooled rows), 7 band-tiles/img -> a2 hi/lo
        conv_mfma_halo<128, 128, 30, 4, 2, 2><<<bc * 7, 256, 0, stream>>>(
            a1hi, a1lo, wB2, SC[1], SH[1], nullptr, a2hi, a2lo);

        // L3: whole-plane tile (TMR=12, MSPW=3) -> a3 hi/lo
        conv_mfma_halo<128, 256, 14, 12, 3, 1><<<bc * 2, 256, 0, stream>>>(
            a2hi, a2lo, wB3, SC[2], SH[2], nullptr, a3hi, a3lo);

        // L4 + fused pool: whole-plane tile (10 rows -> 5 pooled) -> persistent a4
        conv_mfma_halo<256, 256, 12, 10, 2, 2><<<bc * 2, 256, 0, stream>>>(
            a3hi, a3lo, wB4, SC[3], SH[3], nullptr,
            a4hi + (size_t)b0 * 6400, a4lo + (size_t)b0 * 6400);
    }

    // L5: full batch, one launch. M=512*9=4608, grid 144 blocks.
    conv_mfma<256, 512, 5, 1><<<cdiv(512LL * 9, 128) * 4, 256, 0, stream>>>(
        a4hi, a4lo, wB5, SC[4], SH[4], nullptr, y5hi, y5lo, 512 * 9, 4);

    // ---- FC chain, full batch, split-K MFMA ----
    fc_mfma_split<8><<<256, 256, 0, stream>>>(y5hi, y5lo, wB6, fcpart, 512, 4608, 4, 9);
    fc_reduce<1><<<cdiv(512LL * 512, TB), TB, 0, stream>>>(
        fcpart, 16, SC[5], SH[5], nullptr, t6hi, t6lo, 512, 512, 512, 1);
    fc_mfma_split<8><<<256, 256, 0, stream>>>(t6hi, t6lo, wF1, fcpart, 512, 512, 8, 2);
    fc_reduce<1><<<cdiv(512LL * 1024, TB), TB, 0, stream>>>(
        fcpart, 8, nullptr, fb1, nullptr, f1hi, f1lo, 512, 1024, 1024, 1);
    fc_mfma_split<8><<<256, 256, 0, stream>>>(f1hi, f1lo, wF2, fcpart, 512, 1024, 8, 4);
    fc_reduce<1><<<cdiv(512LL * 1024, TB), TB, 0, stream>>>(
        fcpart, 8, nullptr, fb2, nullptr, f2hi, f2lo, 512, 1024, 1024, 1);
    fc_mfma_split<1><<<64, 256, 0, stream>>>(f2hi, f2lo, wF3, fcpart, 512, 1024, 1, 2);
    fc_reduce<0><<<cdiv(512LL * 10, TB), TB, 0, stream>>>(
        fcpart, 16, nullptr, fb3, logits, nullptr, nullptr, 512, 10, 16, 0);
    softmax10_kernel<<<cdiv(512LL, TB), TB, 0, stream>>>(logits, out, 512);
}